// Round 3
// baseline (433.886 us; speedup 1.0000x reference)
//
#include <hip/hip_runtime.h>

// DisplacementVectorsASU: out[i] = frac[e0[i]] - ( wrap(symm[i][0:3] @ [frac[e1[i]],1]) + ct[i] )
// wrap(x) = x - floor(x).
//
// Memory-bound streaming (~390 MB/launch -> ~61 us floor @6.3 TB/s) + 8M random
// 12B gathers into a 1.2MB node table.
//
// R3 = R2 with native vector type for nontemporal builtins (HIP float4 is a
// class -> rejected by __builtin_nontemporal_*; ext_vector_type(4) works).

typedef float vf4 __attribute__((ext_vector_type(4)));

__global__ __launch_bounds__(256) void pad_frac_kernel(
    const float* __restrict__ frac, vf4* __restrict__ fracp, int N)
{
    int i = blockIdx.x * blockDim.x + threadIdx.x;
    if (i < N) {
        vf4 v;
        v.x = frac[3 * i + 0];
        v.y = frac[3 * i + 1];
        v.z = frac[3 * i + 2];
        v.w = 0.0f;
        fracp[i] = v;
    }
}

// Full 256-edge tiles only (M % 256 handled by tail kernel).
__global__ __launch_bounds__(256) void disp_vec_main(
    const vf4*   __restrict__ fracp,   // (N) padded nodes
    const int*   __restrict__ eidx,    // (2,M)
    const float* __restrict__ symm,    // (M,4,4)
    const float* __restrict__ ct,      // (M,3)
    float*       __restrict__ out,     // (M,3)
    int M)
{
    __shared__ float lds[768];          // one 256-edge tile of 3-vectors
    const int tid  = threadIdx.x;
    const int base = blockIdx.x * 256;
    const int i    = base + tid;

    // ---- stage ct tile into LDS: 192 coalesced float4 loads (16B-aligned: base*12B) ----
    if (tid < 192) {
        const vf4* c4 = (const vf4*)(ct + (size_t)base * 3);
        ((vf4*)lds)[tid] = __builtin_nontemporal_load(c4 + tid);
    }

    // ---- streamed per-edge operands (nt: read once, don't pollute L2) ----
    const int n0 = __builtin_nontemporal_load(eidx + i);
    const int n1 = __builtin_nontemporal_load(eidx + M + i);

    const vf4* s = (const vf4*)(symm + (size_t)i * 16);
    const vf4 r0 = __builtin_nontemporal_load(s + 0);
    const vf4 r1 = __builtin_nontemporal_load(s + 1);
    const vf4 r2 = __builtin_nontemporal_load(s + 2);

    // ---- gathers: single dwordx4 each, L2-resident table ----
    const vf4 fin = fracp[n0];
    const vf4 fo  = fracp[n1];

    float t0 = fo.x * r0.x + fo.y * r0.y + fo.z * r0.z + r0.w;
    float t1 = fo.x * r1.x + fo.y * r1.y + fo.z * r1.z + r1.w;
    float t2 = fo.x * r2.x + fo.y * r2.y + fo.z * r2.z + r2.w;

    t0 -= floorf(t0);
    t1 -= floorf(t1);
    t2 -= floorf(t2);

    __syncthreads();                    // ct tile visible
    const float c0 = lds[3 * tid + 0];  // stride-3: 2-way bank aliasing = free
    const float c1 = lds[3 * tid + 1];
    const float c2 = lds[3 * tid + 2];

    const float o0 = fin.x - (t0 + c0);
    const float o1 = fin.y - (t1 + c1);
    const float o2 = fin.z - (t2 + c2);

    __syncthreads();                    // everyone done reading ct before overwrite
    lds[3 * tid + 0] = o0;
    lds[3 * tid + 1] = o1;
    lds[3 * tid + 2] = o2;
    __syncthreads();

    // ---- write out tile: 192 coalesced float4 nt-stores ----
    if (tid < 192) {
        vf4* o4 = (vf4*)(out + (size_t)base * 3);
        __builtin_nontemporal_store(((vf4*)lds)[tid], o4 + tid);
    }
    (void)M;
}

// Scalar tail (and fallback if ws is too small) — same math as R1.
__global__ __launch_bounds__(256) void disp_vec_scalar(
    const float* __restrict__ frac,
    const int*   __restrict__ eidx,
    const float* __restrict__ symm,
    const float* __restrict__ ct,
    float*       __restrict__ out,
    int M, int start)
{
    int i = start + blockIdx.x * blockDim.x + threadIdx.x;
    if (i >= M) return;

    int n0 = eidx[i];
    int n1 = eidx[M + i];

    const float* f0 = frac + (size_t)n0 * 3;
    const float* f1 = frac + (size_t)n1 * 3;

    const float4* s = (const float4*)(symm + (size_t)i * 16);
    float4 r0 = s[0], r1 = s[1], r2 = s[2];

    float ox = f1[0], oy = f1[1], oz = f1[2];
    float t0 = ox * r0.x + oy * r0.y + oz * r0.z + r0.w;
    float t1 = ox * r1.x + oy * r1.y + oz * r1.z + r1.w;
    float t2 = ox * r2.x + oy * r2.y + oz * r2.z + r2.w;

    t0 -= floorf(t0);
    t1 -= floorf(t1);
    t2 -= floorf(t2);

    const float* c = ct + (size_t)i * 3;
    float* o = out + (size_t)i * 3;
    o[0] = f0[0] - (t0 + c[0]);
    o[1] = f0[1] - (t1 + c[1]);
    o[2] = f0[2] - (t2 + c[2]);
}

extern "C" void kernel_launch(void* const* d_in, const int* in_sizes, int n_in,
                              void* d_out, int out_size, void* d_ws, size_t ws_size,
                              hipStream_t stream) {
    const float* frac = (const float*)d_in[0];   // (N,3) f32
    const int*   eidx = (const int*)d_in[1];     // (2,M) i32
    const float* symm = (const float*)d_in[2];   // (M,4,4) f32
    const float* ct   = (const float*)d_in[3];   // (M,3) f32
    float* out = (float*)d_out;                  // (M,3) f32

    const int N = in_sizes[0] / 3;               // 100,000 nodes
    const int M = in_sizes[1] / 2;               // 4,000,000 edges

    const size_t need = (size_t)N * sizeof(vf4);
    if (ws_size >= need) {
        vf4* fracp = (vf4*)d_ws;
        pad_frac_kernel<<<(N + 255) / 256, 256, 0, stream>>>(frac, fracp, N);

        const int full_tiles = M / 256;
        const int rem        = M % 256;          // 0 for M = 4,000,000
        if (full_tiles > 0) {
            disp_vec_main<<<full_tiles, 256, 0, stream>>>(fracp, eidx, symm, ct, out, M);
        }
        if (rem > 0) {
            disp_vec_scalar<<<1, 256, 0, stream>>>(frac, eidx, symm, ct, out, M, full_tiles * 256);
        }
    } else {
        disp_vec_scalar<<<(M + 255) / 256, 256, 0, stream>>>(frac, eidx, symm, ct, out, M, 0);
    }
}

// Round 4
// 418.129 us; speedup vs baseline: 1.0377x; 1.0377x over previous
//
#include <hip/hip_runtime.h>

// DisplacementVectorsASU: out[i] = frac[e0[i]] - ( wrap(symm[i][0:3] @ [frac[e1[i]],1]) + ct[i] )
// wrap(x) = x - floor(x).
//
// R4: symm is read with fully-contiguous coalesced dwordx4 loads into a skewed
// LDS tile (was: 3 stride-64B loads/lane = 192 divergent 64B sector requests
// per wave -> suspected TA/L2 request-rate bottleneck). Row reads from LDS use
// skew p = s + s/8 so lanes spread over all 8 bank quads (min conflicts).
// Gathers stay as single dwordx4 into the float4-padded node table in d_ws.

typedef float vf4 __attribute__((ext_vector_type(4)));

__global__ __launch_bounds__(256) void pad_frac_kernel(
    const float* __restrict__ frac, vf4* __restrict__ fracp, int N)
{
    int i = blockIdx.x * blockDim.x + threadIdx.x;
    if (i < N) {
        vf4 v;
        v.x = frac[3 * i + 0];
        v.y = frac[3 * i + 1];
        v.z = frac[3 * i + 2];
        v.w = 0.0f;
        fracp[i] = v;
    }
}

// Full 256-edge tiles only (tail handled by scalar kernel).
__global__ __launch_bounds__(256) void disp_vec_main(
    const vf4*   __restrict__ fracp,   // (N) padded nodes, L2-resident
    const int*   __restrict__ eidx,    // (2,M)
    const float* __restrict__ symm,    // (M,4,4)
    const float* __restrict__ ct,      // (M,3)
    float*       __restrict__ out,     // (M,3)
    int M)
{
    // symm tile: 256 edges * 4 rows = 1024 vf4, skewed (+1 slot per 8) = 1152
    __shared__ vf4   sy[1152];          // 18432 B
    __shared__ float so[768];           // out staging, 3072 B

    const int tid  = threadIdx.x;
    const int base = blockIdx.x * 256;
    const int i    = base + tid;

    // ---- stage symm tile: 4 fully-contiguous vf4 loads per thread ----
    const vf4* sg = (const vf4*)(symm + (size_t)base * 16);
    #pragma unroll
    for (int k = 0; k < 4; ++k) {
        const int slot = k * 256 + tid;
        sy[slot + (slot >> 3)] = sg[slot];
    }

    // ---- per-edge streamed operands (coalesced) ----
    const int n0 = eidx[i];
    const int n1 = eidx[M + i];
    const float c0 = ct[3 * (size_t)i + 0];
    const float c1 = ct[3 * (size_t)i + 1];
    const float c2 = ct[3 * (size_t)i + 2];

    // ---- gathers: single dwordx4 each ----
    const vf4 fin = fracp[n0];
    const vf4 fo  = fracp[n1];

    __syncthreads();                    // symm tile visible

    const int s0 = 4 * tid;
    const vf4 r0 = sy[s0     + ((s0    ) >> 3)];
    const vf4 r1 = sy[s0 + 1 + ((s0 + 1) >> 3)];
    const vf4 r2 = sy[s0 + 2 + ((s0 + 2) >> 3)];

    float t0 = fo.x * r0.x + fo.y * r0.y + fo.z * r0.z + r0.w;
    float t1 = fo.x * r1.x + fo.y * r1.y + fo.z * r1.z + r1.w;
    float t2 = fo.x * r2.x + fo.y * r2.y + fo.z * r2.z + r2.w;

    t0 -= floorf(t0);
    t1 -= floorf(t1);
    t2 -= floorf(t2);

    so[3 * tid + 0] = fin.x - (t0 + c0);
    so[3 * tid + 1] = fin.y - (t1 + c1);
    so[3 * tid + 2] = fin.z - (t2 + c2);
    __syncthreads();

    // ---- write out tile: 192 coalesced vf4 nt-stores ----
    if (tid < 192) {
        vf4* o4 = (vf4*)(out + (size_t)base * 3);
        __builtin_nontemporal_store(((vf4*)so)[tid], o4 + tid);
    }
    (void)M;
}

// Scalar tail / fallback — same math.
__global__ __launch_bounds__(256) void disp_vec_scalar(
    const float* __restrict__ frac,
    const int*   __restrict__ eidx,
    const float* __restrict__ symm,
    const float* __restrict__ ct,
    float*       __restrict__ out,
    int M, int start)
{
    int i = start + blockIdx.x * blockDim.x + threadIdx.x;
    if (i >= M) return;

    int n0 = eidx[i];
    int n1 = eidx[M + i];

    const float* f0 = frac + (size_t)n0 * 3;
    const float* f1 = frac + (size_t)n1 * 3;

    const float4* s = (const float4*)(symm + (size_t)i * 16);
    float4 r0 = s[0], r1 = s[1], r2 = s[2];

    float ox = f1[0], oy = f1[1], oz = f1[2];
    float t0 = ox * r0.x + oy * r0.y + oz * r0.z + r0.w;
    float t1 = ox * r1.x + oy * r1.y + oz * r1.z + r1.w;
    float t2 = ox * r2.x + oy * r2.y + oz * r2.z + r2.w;

    t0 -= floorf(t0);
    t1 -= floorf(t1);
    t2 -= floorf(t2);

    const float* c = ct + (size_t)i * 3;
    float* o = out + (size_t)i * 3;
    o[0] = f0[0] - (t0 + c[0]);
    o[1] = f0[1] - (t1 + c[1]);
    o[2] = f0[2] - (t2 + c[2]);
}

extern "C" void kernel_launch(void* const* d_in, const int* in_sizes, int n_in,
                              void* d_out, int out_size, void* d_ws, size_t ws_size,
                              hipStream_t stream) {
    const float* frac = (const float*)d_in[0];   // (N,3) f32
    const int*   eidx = (const int*)d_in[1];     // (2,M) i32
    const float* symm = (const float*)d_in[2];   // (M,4,4) f32
    const float* ct   = (const float*)d_in[3];   // (M,3) f32
    float* out = (float*)d_out;                  // (M,3) f32

    const int N = in_sizes[0] / 3;               // 100,000 nodes
    const int M = in_sizes[1] / 2;               // 4,000,000 edges

    const size_t need = (size_t)N * sizeof(vf4);
    if (ws_size >= need) {
        vf4* fracp = (vf4*)d_ws;
        pad_frac_kernel<<<(N + 255) / 256, 256, 0, stream>>>(frac, fracp, N);

        const int full_tiles = M / 256;
        const int rem        = M % 256;          // 0 for M = 4,000,000
        if (full_tiles > 0) {
            disp_vec_main<<<full_tiles, 256, 0, stream>>>(fracp, eidx, symm, ct, out, M);
        }
        if (rem > 0) {
            disp_vec_scalar<<<1, 256, 0, stream>>>(frac, eidx, symm, ct, out, M, full_tiles * 256);
        }
    } else {
        disp_vec_scalar<<<(M + 255) / 256, 256, 0, stream>>>(frac, eidx, symm, ct, out, M, 0);
    }
}